// Round 1
// baseline (10587.614 us; speedup 1.0000x reference)
//
#include <hip/hip_runtime.h>

// ---------------- workspace layout (floats) ----------------
#define N_FEAT   (4ull*320*640*32)            // 26,214,400
#define WS_FEAT  0ull
#define WS_COSTS (N_FEAT)                     // 26,214,400
#define N_COSTS  (4ull*256*256*128)           // 33,554,432
#define WS_X1    0ull                         // reuse feat region (needs 16,777,216)
#define WS_X2    (WS_COSTS)                   // reuse costs region (needs 8,388,608)
#define N_X2     (4ull*256*256*32)
#define WS_X3    (WS_COSTS + N_X2)            // 34,603,008 (needs 262,144)
#define WS_WTF   (WS_COSTS + N_COSTS)         // 59,768,832
#define N_WTF    (27*128*64)                  // 221,184
#define WS_WT1   (WS_WTF + N_WTF)
#define N_WT1    (27*64*32)                   // 55,296
#define WS_WT2   (WS_WT1 + N_WT1)

// transpose OIDHW -> [kpos][ci][co]
__global__ void omni_transpose_w(const float* __restrict__ src, float* __restrict__ dst,
                                 int cin, int cout, int n) {
    int i = blockIdx.x * 256 + threadIdx.x;
    if (i >= n) return;
    int co = i % cout;
    int t  = i / cout;
    int ci = t % cin;
    int kpos = t / cin;
    dst[i] = src[(co * cin + ci) * 27 + kpos];
}

// conv2d stride2 pad1 + relu; input NCHW [3,640,1280]; out channels-last [cam][320][640][32]
__global__ __launch_bounds__(256) void omni_feat_conv(
        const float* __restrict__ c0, const float* __restrict__ c1,
        const float* __restrict__ c2, const float* __restrict__ c3,
        const float* __restrict__ w, float* __restrict__ feat) {
    __shared__ float wl[864];
    int tid = threadIdx.x;
    for (int i = tid; i < 864; i += 256) wl[i] = w[i];
    __syncthreads();
    int gid = blockIdx.x * 256 + tid;               // 4*320*640
    int ox = gid % 640;
    int t = gid / 640;
    int oy = t % 320;
    int cam = t / 320;
    const float* src = (cam == 0) ? c0 : (cam == 1) ? c1 : (cam == 2) ? c2 : c3;
    float acc[32];
#pragma unroll
    for (int i = 0; i < 32; i++) acc[i] = 0.f;
    for (int ky = 0; ky < 3; ky++) {
        int iy = oy * 2 - 1 + ky;
        if (iy < 0 || iy >= 640) continue;
        for (int kx = 0; kx < 3; kx++) {
            int ix = ox * 2 - 1 + kx;
            if (ix < 0 || ix >= 1280) continue;
#pragma unroll
            for (int ci = 0; ci < 3; ci++) {
                float v = src[(ci * 640 + iy) * 1280 + ix];
#pragma unroll
                for (int co = 0; co < 32; co++)
                    acc[co] += v * wl[((co * 3 + ci) * 3 + ky) * 3 + kx];
            }
        }
    }
    float4* d4 = (float4*)(feat + (size_t)gid * 32);
#pragma unroll
    for (int q = 0; q < 8; q++)
        d4[q] = make_float4(fmaxf(acc[4*q],0.f), fmaxf(acc[4*q+1],0.f),
                            fmaxf(acc[4*q+2],0.f), fmaxf(acc[4*q+3],0.f));
}

// fused grid_sample + antialiased bilinear resize (320x640 -> 256x256)
// feat channels-last [cam][320][640][32]; costs [d][256][256][128] (cam*32+c)
__global__ __launch_bounds__(256) void omni_warp_resize(
        const float* __restrict__ feat, const float* __restrict__ grids,
        float* __restrict__ costs) {
    int gid = blockIdx.x * 256 + threadIdx.x;       // 4*4*256*256
    int x = gid & 255;
    int y = (gid >> 8) & 255;
    int d = (gid >> 16) & 3;
    int cam = gid >> 18;

    // H taps: kernel_scale 1.25
    float sy = 1.25f * y + 0.125f;
    int jy0 = (int)ceilf(sy - 1.25f);
    float wy[3]; float sumy = 0.f;
#pragma unroll
    for (int t = 0; t < 3; t++) {
        int j = jy0 + t;
        float w = fmaxf(1.f - fabsf(sy - (float)j) * 0.8f, 0.f);
        if (j < 0 || j > 319) w = 0.f;
        wy[t] = w; sumy += w;
    }
    float isy = 1.f / sumy;
    // W taps: kernel_scale 2.5
    float sx = 2.5f * x + 0.75f;
    int jx0 = (int)ceilf(sx - 2.5f);
    float wx[5]; float sumx = 0.f;
#pragma unroll
    for (int t = 0; t < 5; t++) {
        int j = jx0 + t;
        float w = fmaxf(1.f - fabsf(sx - (float)j) * 0.4f, 0.f);
        if (j < 0 || j > 639) w = 0.f;
        wx[t] = w; sumx += w;
    }
    float isx = 1.f / sumx;

    float4 acc[8];
#pragma unroll
    for (int q = 0; q < 8; q++) acc[q] = make_float4(0.f,0.f,0.f,0.f);
    const float* gbase = grids + ((size_t)(cam * 4 + d) * 320) * 640 * 2;
    const float* fbase = feat + (size_t)cam * 320 * 640 * 32;

#pragma unroll
    for (int a = 0; a < 3; a++) {
        int jy = jy0 + a;
        float wya = wy[a] * isy;
        if (wya <= 0.f) continue;
        const float* grow = gbase + (size_t)jy * 640 * 2;
#pragma unroll
        for (int b = 0; b < 5; b++) {
            float wr = wya * wx[b] * isx;
            if (wr <= 0.f) continue;
            int jx = jx0 + b;
            float gx = grow[jx * 2];
            float gy = grow[jx * 2 + 1];
            float fx = (gx + 1.f) * 320.f - 0.5f;
            float fy = (gy + 1.f) * 160.f - 0.5f;
            float x0f = floorf(fx), y0f = floorf(fy);
            float ax = fx - x0f, ay = fy - y0f;
            int x0 = (int)x0f, y0 = (int)y0f;
            float tw[4] = {(1.f-ax)*(1.f-ay), ax*(1.f-ay), (1.f-ax)*ay, ax*ay};
            int xs4[4] = {x0, x0+1, x0, x0+1};
            int ys4[4] = {y0, y0, y0+1, y0+1};
#pragma unroll
            for (int tc = 0; tc < 4; tc++) {
                int xi = xs4[tc], yi = ys4[tc];
                if (xi < 0 || xi >= 640 || yi < 0 || yi >= 320) continue;
                float wt = wr * tw[tc];
                const float4* f4 = (const float4*)(fbase + ((size_t)yi * 640 + xi) * 32);
#pragma unroll
                for (int q = 0; q < 8; q++) {
                    float4 v = f4[q];
                    acc[q].x += wt * v.x; acc[q].y += wt * v.y;
                    acc[q].z += wt * v.z; acc[q].w += wt * v.w;
                }
            }
        }
    }
    float4* d4 = (float4*)(costs + (((size_t)(d * 256 + y) * 256 + x) * 128) + cam * 32);
#pragma unroll
    for (int q = 0; q < 8; q++) d4[q] = acc[q];
}

// generic channels-last conv3d pad1; wt layout [kpos][ci][co]; block: 64 px * COUT
template<int CIN, int COUT, int RELU>
__global__ __launch_bounds__(256) void omni_conv3d(
        const float* __restrict__ in, const float* __restrict__ wt,
        float* __restrict__ out) {
    constexpr int NTH = 16 * (COUT / 4);
    __shared__ float wl[CIN * COUT];
    int tid = threadIdx.x;
    int pxg = tid & 15;
    int cog = tid >> 4;
    int bid = blockIdx.x;
    int xt = bid & 3;
    int y = (bid >> 2) & 255;
    int d = bid >> 10;
    int xs = xt * 64 + pxg * 4;
    int co0 = cog * 4;
    float4 acc[4];
#pragma unroll
    for (int p = 0; p < 4; p++) acc[p] = make_float4(0.f,0.f,0.f,0.f);

    for (int kd = 0; kd < 3; kd++) {
        int dd = d + kd - 1;
        if (dd < 0 || dd > 3) continue;              // block-uniform
        for (int ky = 0; ky < 3; ky++) {
            int yy = y + ky - 1;
            if (yy < 0 || yy > 255) continue;        // block-uniform
            for (int kx = 0; kx < 3; kx++) {
                int kpos = (kd * 3 + ky) * 3 + kx;
                const float* wsrc = wt + (size_t)kpos * CIN * COUT;
                __syncthreads();
                for (int i = tid; i < CIN * COUT; i += NTH) wl[i] = wsrc[i];
                __syncthreads();
                const float* ib[4]; bool val[4];
#pragma unroll
                for (int p = 0; p < 4; p++) {
                    int xx = xs + p + kx - 1;
                    val[p] = (xx >= 0 && xx < 256);
                    ib[p] = in + (((size_t)dd * 256 + yy) * 256 + (val[p] ? xx : 0)) * CIN;
                }
                for (int cq = 0; cq < CIN / 4; cq++) {
                    float4 a[4];
#pragma unroll
                    for (int p = 0; p < 4; p++)
                        a[p] = val[p] ? ((const float4*)ib[p])[cq] : make_float4(0.f,0.f,0.f,0.f);
#pragma unroll
                    for (int c = 0; c < 4; c++) {
                        float4 wv = *(const float4*)&wl[(cq * 4 + c) * COUT + co0];
#pragma unroll
                        for (int p = 0; p < 4; p++) {
                            float av = (c==0) ? a[p].x : (c==1) ? a[p].y : (c==2) ? a[p].z : a[p].w;
                            acc[p].x += av * wv.x; acc[p].y += av * wv.y;
                            acc[p].z += av * wv.z; acc[p].w += av * wv.w;
                        }
                    }
                }
            }
        }
    }
#pragma unroll
    for (int p = 0; p < 4; p++) {
        float4 v = acc[p];
        if (RELU) { v.x=fmaxf(v.x,0.f); v.y=fmaxf(v.y,0.f); v.z=fmaxf(v.z,0.f); v.w=fmaxf(v.w,0.f); }
        *(float4*)(out + (((size_t)d * 256 + y) * 256 + xs + p) * COUT + co0) = v;
    }
}

// conv3d 32->1, wt2 [kpos][ci]
__global__ __launch_bounds__(256) void omni_reg2(
        const float* __restrict__ in, const float* __restrict__ wt2,
        float* __restrict__ out) {
    __shared__ float wl[27 * 32];
    int tid = threadIdx.x;
    for (int i = tid; i < 864; i += 256) wl[i] = wt2[i];
    __syncthreads();
    int gid = blockIdx.x * 256 + tid;               // 4*256*256
    int x = gid & 255;
    int y = (gid >> 8) & 255;
    int d = gid >> 16;
    float acc = 0.f;
    for (int kd = 0; kd < 3; kd++) {
        int dd = d + kd - 1; if (dd < 0 || dd > 3) continue;
        for (int ky = 0; ky < 3; ky++) {
            int yy = y + ky - 1; if (yy < 0 || yy > 255) continue;
            for (int kx = 0; kx < 3; kx++) {
                int xx = x + kx - 1; if (xx < 0 || xx > 255) continue;
                const float4* f4 = (const float4*)(in + (((size_t)dd * 256 + yy) * 256 + xx) * 32);
                const float* wp = &wl[((kd * 3 + ky) * 3 + kx) * 32];
#pragma unroll
                for (int q = 0; q < 8; q++) {
                    float4 v = f4[q];
                    acc += v.x * wp[4*q] + v.y * wp[4*q+1] + v.z * wp[4*q+2] + v.w * wp[4*q+3];
                }
            }
        }
    }
    out[gid] = acc;
}

// depth resize 4->8 (triangle, normalized) + softmax + expectation
__global__ __launch_bounds__(256) void omni_disp(
        const float* __restrict__ x3, float* __restrict__ out) {
    int gid = blockIdx.x * 256 + threadIdx.x;       // 65536
    float v0 = x3[gid];
    float v1 = x3[65536 + gid];
    float v2 = x3[2 * 65536 + gid];
    float v3 = x3[3 * 65536 + gid];
    float l[8];
    l[0] = v0;
    l[1] = 0.75f * v0 + 0.25f * v1;
    l[2] = 0.25f * v0 + 0.75f * v1;
    l[3] = 0.75f * v1 + 0.25f * v2;
    l[4] = 0.25f * v1 + 0.75f * v2;
    l[5] = 0.75f * v2 + 0.25f * v3;
    l[6] = 0.25f * v2 + 0.75f * v3;
    l[7] = v3;
    float m = l[0];
#pragma unroll
    for (int i = 1; i < 8; i++) m = fmaxf(m, l[i]);
    float s = 0.f, e = 0.f;
#pragma unroll
    for (int i = 0; i < 8; i++) {
        float p = expf(l[i] - m);
        s += p; e += p * (float)i;
    }
    out[gid] = e / s;
}

extern "C" void kernel_launch(void* const* d_in, const int* in_sizes, int n_in,
                              void* d_out, int out_size, void* d_ws, size_t ws_size,
                              hipStream_t stream) {
    const float* cam0 = (const float*)d_in[0];
    const float* cam1 = (const float*)d_in[1];
    const float* cam2 = (const float*)d_in[2];
    const float* cam3 = (const float*)d_in[3];
    const float* grids = (const float*)d_in[4];
    const float* w_feat = (const float*)d_in[5];
    const float* w_fusion = (const float*)d_in[6];
    const float* w_reg1 = (const float*)d_in[7];
    const float* w_reg2 = (const float*)d_in[8];
    float* ws = (float*)d_ws;
    float* feat  = ws + WS_FEAT;
    float* costs = ws + WS_COSTS;
    float* x1    = ws + WS_X1;
    float* x2    = ws + WS_X2;
    float* x3    = ws + WS_X3;
    float* wtf   = ws + WS_WTF;
    float* wt1   = ws + WS_WT1;
    float* wt2   = ws + WS_WT2;

    omni_transpose_w<<<(27*128*64 + 255)/256, 256, 0, stream>>>(w_fusion, wtf, 128, 64, 27*128*64);
    omni_transpose_w<<<(27*64*32 + 255)/256, 256, 0, stream>>>(w_reg1, wt1, 64, 32, 27*64*32);
    omni_transpose_w<<<(27*32 + 255)/256, 256, 0, stream>>>(w_reg2, wt2, 32, 1, 27*32);

    omni_feat_conv<<<3200, 256, 0, stream>>>(cam0, cam1, cam2, cam3, w_feat, feat);
    omni_warp_resize<<<4096, 256, 0, stream>>>(feat, grids, costs);
    omni_conv3d<128, 64, 1><<<4096, 256, 0, stream>>>(costs, wtf, x1);
    omni_conv3d<64, 32, 1><<<4096, 128, 0, stream>>>(x1, wt1, x2);
    omni_reg2<<<1024, 256, 0, stream>>>(x2, wt2, x3);
    omni_disp<<<256, 256, 0, stream>>>(x3, (float*)d_out);
}

// Round 2
// 1088.015 us; speedup vs baseline: 9.7311x; 9.7311x over previous
//
#include <hip/hip_runtime.h>

typedef __attribute__((ext_vector_type(8))) __bf16 bfrag;
typedef __attribute__((ext_vector_type(16))) float f32x16;
typedef unsigned short ushort_t;

__device__ __forceinline__ float bf2f(unsigned short h) {
    union { unsigned int u; float f; } c; c.u = ((unsigned int)h) << 16; return c.f;
}
__device__ __forceinline__ unsigned short f2bf(float f) {
    union { unsigned int u; float f; } c; c.f = f;
    unsigned int u = c.u;
    return (unsigned short)((u + 0x7FFFu + ((u >> 16) & 1u)) >> 16);
}
__device__ __forceinline__ float2 bfp(unsigned int u) {
    union { unsigned int u; float f; } lo, hi;
    lo.u = u << 16; hi.u = u & 0xFFFF0000u;
    return make_float2(lo.f, hi.f);
}

// ---------------- workspace layout (bytes) ----------------
// feat  bf16 [4][320][640][32]   at 0          (52,428,800)
// costs bf16 [4][256][256][128]  at 52428800   (67,108,864)
// x1    bf16 [4][256][256][64]   at 119537664  (33,554,432)
// x2    bf16 [4][256][256][32]   at 153092096  (16,777,216)
// x3    f32  [4][256][256]       at 169869312  (1,048,576)
// wbf   bf16 packed fusion       at 170917888  (442,368)
// wb1   bf16 packed reg1         at 171360256  (110,592)
// wt2   f32  [kpos][32]          at 171470848  (3,456)

// transpose OIDHW -> [kpos][ci] (cout==1 use)
__global__ void omni_transpose_w(const float* __restrict__ src, float* __restrict__ dst,
                                 int cin, int cout, int n) {
    int i = blockIdx.x * 256 + threadIdx.x;
    if (i >= n) return;
    int co = i % cout;
    int t  = i / cout;
    int ci = t % cin;
    int kpos = t / cin;
    dst[i] = src[(co * cin + ci) * 27 + kpos];
}

// pack conv3d weights (OIDHW fp32) into MFMA B-fragment order, bf16.
// layout: [p = c*3+kd][f = tap*4+ks][wn][lane][8]
template<int CI, int CO>
__global__ void omni_pack_w(const float* __restrict__ w, ushort_t* __restrict__ dst) {
    constexpr int WN = CO / 32;
    const int n = (CI / 64) * 3 * 36 * WN * 512;
    int o = blockIdx.x * 256 + threadIdx.x;
    if (o >= n) return;
    const int j = o & 7;
    const int lane = (o >> 3) & 63;
    int r = o >> 9;
    const int wn = r % WN; r /= WN;
    const int f = r % 36;  const int p = r / 36;
    const int tap = f >> 2, ks = f & 3;
    const int c = p / 3, kd = p % 3;
    const int co = wn * 32 + (lane & 31);
    const int ci = c * 64 + ks * 16 + (lane >> 5) * 8 + j;
    const int ky = tap / 3, kx = tap % 3;
    dst[o] = f2bf(w[(((size_t)(co * CI + ci) * 3 + kd) * 3 + ky) * 3 + kx]);
}

// conv2d stride2 pad1 + relu; input NCHW [3,640,1280]; out bf16 channels-last [cam][320][640][32]
__global__ __launch_bounds__(256) void omni_feat_conv(
        const float* __restrict__ c0, const float* __restrict__ c1,
        const float* __restrict__ c2, const float* __restrict__ c3,
        const float* __restrict__ w, ushort_t* __restrict__ feat) {
    __shared__ float wl[864];
    int tid = threadIdx.x;
    for (int i = tid; i < 864; i += 256) wl[i] = w[i];
    __syncthreads();
    int gid = blockIdx.x * 256 + tid;               // 4*320*640
    int ox = gid % 640;
    int t = gid / 640;
    int oy = t % 320;
    int cam = t / 320;
    const float* src = (cam == 0) ? c0 : (cam == 1) ? c1 : (cam == 2) ? c2 : c3;
    float acc[32];
#pragma unroll
    for (int i = 0; i < 32; i++) acc[i] = 0.f;
    for (int ky = 0; ky < 3; ky++) {
        int iy = oy * 2 - 1 + ky;
        if (iy < 0 || iy >= 640) continue;
        for (int kx = 0; kx < 3; kx++) {
            int ix = ox * 2 - 1 + kx;
            if (ix < 0 || ix >= 1280) continue;
#pragma unroll
            for (int ci = 0; ci < 3; ci++) {
                float v = src[(ci * 640 + iy) * 1280 + ix];
#pragma unroll
                for (int co = 0; co < 32; co++)
                    acc[co] += v * wl[((co * 3 + ci) * 3 + ky) * 3 + kx];
            }
        }
    }
    uint4* d4 = (uint4*)(feat + (size_t)gid * 32);
#pragma unroll
    for (int q = 0; q < 4; q++) {
        uint4 v;
        v.x = ((unsigned)f2bf(fmaxf(acc[8*q+1],0.f)) << 16) | f2bf(fmaxf(acc[8*q+0],0.f));
        v.y = ((unsigned)f2bf(fmaxf(acc[8*q+3],0.f)) << 16) | f2bf(fmaxf(acc[8*q+2],0.f));
        v.z = ((unsigned)f2bf(fmaxf(acc[8*q+5],0.f)) << 16) | f2bf(fmaxf(acc[8*q+4],0.f));
        v.w = ((unsigned)f2bf(fmaxf(acc[8*q+7],0.f)) << 16) | f2bf(fmaxf(acc[8*q+6],0.f));
        d4[q] = v;
    }
}

// fused grid_sample + antialiased bilinear resize (320x640 -> 256x256), bf16 in/out
__global__ __launch_bounds__(256) void omni_warp_resize(
        const ushort_t* __restrict__ feat, const float* __restrict__ grids,
        ushort_t* __restrict__ costs) {
    int gid = blockIdx.x * 256 + threadIdx.x;       // 4*4*256*256
    int x = gid & 255;
    int y = (gid >> 8) & 255;
    int d = (gid >> 16) & 3;
    int cam = gid >> 18;

    float sy = 1.25f * y + 0.125f;
    int jy0 = (int)ceilf(sy - 1.25f);
    float wy[3]; float sumy = 0.f;
#pragma unroll
    for (int t = 0; t < 3; t++) {
        int j = jy0 + t;
        float w = fmaxf(1.f - fabsf(sy - (float)j) * 0.8f, 0.f);
        if (j < 0 || j > 319) w = 0.f;
        wy[t] = w; sumy += w;
    }
    float isy = 1.f / sumy;
    float sx = 2.5f * x + 0.75f;
    int jx0 = (int)ceilf(sx - 2.5f);
    float wx[5]; float sumx = 0.f;
#pragma unroll
    for (int t = 0; t < 5; t++) {
        int j = jx0 + t;
        float w = fmaxf(1.f - fabsf(sx - (float)j) * 0.4f, 0.f);
        if (j < 0 || j > 639) w = 0.f;
        wx[t] = w; sumx += w;
    }
    float isx = 1.f / sumx;

    float acc[32];
#pragma unroll
    for (int i = 0; i < 32; i++) acc[i] = 0.f;
    const float* gbase = grids + ((size_t)(cam * 4 + d) * 320) * 640 * 2;
    const ushort_t* fbase = feat + (size_t)cam * 320 * 640 * 32;

#pragma unroll
    for (int a = 0; a < 3; a++) {
        int jy = jy0 + a;
        float wya = wy[a] * isy;
        if (wya <= 0.f) continue;
        const float* grow = gbase + (size_t)jy * 640 * 2;
#pragma unroll
        for (int b = 0; b < 5; b++) {
            float wr = wya * wx[b] * isx;
            if (wr <= 0.f) continue;
            int jx = jx0 + b;
            float gx = grow[jx * 2];
            float gy = grow[jx * 2 + 1];
            float fx = (gx + 1.f) * 320.f - 0.5f;
            float fy = (gy + 1.f) * 160.f - 0.5f;
            float x0f = floorf(fx), y0f = floorf(fy);
            float ax = fx - x0f, ay = fy - y0f;
            int x0 = (int)x0f, y0 = (int)y0f;
            float tw[4] = {(1.f-ax)*(1.f-ay), ax*(1.f-ay), (1.f-ax)*ay, ax*ay};
            int xs4[4] = {x0, x0+1, x0, x0+1};
            int ys4[4] = {y0, y0, y0+1, y0+1};
#pragma unroll
            for (int tc = 0; tc < 4; tc++) {
                int xi = xs4[tc], yi = ys4[tc];
                if (xi < 0 || xi >= 640 || yi < 0 || yi >= 320) continue;
                float wt = wr * tw[tc];
                const uint4* f4 = (const uint4*)(fbase + ((size_t)yi * 640 + xi) * 32);
#pragma unroll
                for (int q = 0; q < 4; q++) {
                    uint4 v = f4[q];
                    float2 p0 = bfp(v.x), p1 = bfp(v.y), p2 = bfp(v.z), p3 = bfp(v.w);
                    acc[8*q+0] += wt * p0.x; acc[8*q+1] += wt * p0.y;
                    acc[8*q+2] += wt * p1.x; acc[8*q+3] += wt * p1.y;
                    acc[8*q+4] += wt * p2.x; acc[8*q+5] += wt * p2.y;
                    acc[8*q+6] += wt * p3.x; acc[8*q+7] += wt * p3.y;
                }
            }
        }
    }
    uint4* d4 = (uint4*)(costs + (((size_t)(d * 256 + y) * 256 + x) * 128) + cam * 32);
#pragma unroll
    for (int q = 0; q < 4; q++) {
        uint4 v;
        v.x = ((unsigned)f2bf(acc[8*q+1]) << 16) | f2bf(acc[8*q+0]);
        v.y = ((unsigned)f2bf(acc[8*q+3]) << 16) | f2bf(acc[8*q+2]);
        v.z = ((unsigned)f2bf(acc[8*q+5]) << 16) | f2bf(acc[8*q+4]);
        v.w = ((unsigned)f2bf(acc[8*q+7]) << 16) | f2bf(acc[8*q+6]);
        d4[q] = v;
    }
}

// MFMA implicit-GEMM conv3d (3x3x3, pad1) channels-last bf16, relu.
// block: 128 px (one y row) x CO couts; 4 waves of one 32x32 tile (MT m-tiles each).
// A staged in LDS per (ci64-chunk, kd) with XOR-8 swizzle; B held in registers (36 frags).
template<int CI, int CO>
__global__ __launch_bounds__(256, 2) void omni_conv3d_mfma(
        const ushort_t* __restrict__ in,
        const ushort_t* __restrict__ wb,
        ushort_t* __restrict__ out) {
    constexpr int WN = CO / 32;          // 2 (fusion) or 1 (reg1)
    constexpr int MT = (WN == 2) ? 2 : 1; // m-tiles per wave; block px = 128
    __shared__ ushort_t lds[3 * 130 * 64];
    const int tid = threadIdx.x;
    const int lane = tid & 63;
    const int wid = tid >> 6;
    const int wn = wid & (WN - 1);
    const int wm = wid / WN;
    const int x0 = blockIdx.x * 128;
    const int y  = blockIdx.y;
    const int d  = blockIdx.z;

    f32x16 acc[MT];
#pragma unroll
    for (int mt = 0; mt < MT; ++mt)
#pragma unroll
        for (int r = 0; r < 16; ++r) acc[mt][r] = 0.f;

    bfrag breg[36];

    for (int c = 0; c < CI / 64; ++c) {
        for (int kd = 0; kd < 3; ++kd) {
            const int dd = d + kd - 1;
            if (dd < 0 || dd > 3) continue;            // block-uniform
            __syncthreads();
            // stage [3yy][130x][64ci] swizzled: 3120 x 16B
            for (int i = tid; i < 3120; i += 256) {
                const int g  = i & 7;
                const int xl = (i >> 3) % 130;
                const int yy = (i >> 3) / 130;
                const int gy = y - 1 + yy;
                const int gx = x0 - 1 + xl;
                uint4 v = make_uint4(0u, 0u, 0u, 0u);
                if ((unsigned)gy < 256u && (unsigned)gx < 256u)
                    v = *(const uint4*)(in + (((size_t)dd * 256 + gy) * 256 + gx) * CI + c * 64 + g * 8);
                *(uint4*)&lds[((yy * 130 + xl) * 8 + (g ^ (xl & 7))) * 8] = v;
            }
            // B fragments for this (c,kd): 9 taps x 4 ksteps (registers, no LDS)
            const int p = c * 3 + kd;
#pragma unroll
            for (int f = 0; f < 36; ++f)
                breg[f] = *(const bfrag*)(wb + (((size_t)p * 36 + f) * WN + wn) * 512 + lane * 8);
            __syncthreads();
#pragma unroll
            for (int ky = 0; ky < 3; ++ky) {
                const int gyy = y - 1 + ky;
                if ((unsigned)gyy >= 256u) continue;   // block-uniform
#pragma unroll
                for (int kx = 0; kx < 3; ++kx) {
#pragma unroll
                    for (int ks = 0; ks < 4; ++ks) {
#pragma unroll
                        for (int mt = 0; mt < MT; ++mt) {
                            const int m  = (wm * MT + mt) * 32 + (lane & 31);
                            const int xl = m + kx;
                            const int g  = ks * 2 + (lane >> 5);
                            const bfrag a = *(const bfrag*)&lds[((ky * 130 + xl) * 8 + (g ^ (xl & 7))) * 8];
                            acc[mt] = __builtin_amdgcn_mfma_f32_32x32x16_bf16(
                                a, breg[(ky * 3 + kx) * 4 + ks], acc[mt], 0, 0, 0);
                        }
                    }
                }
            }
        }
    }
    // epilogue: relu + bf16 store. C/D: col=lane&31, row=(r&3)+8*(r>>2)+4*(lane>>5)
#pragma unroll
    for (int mt = 0; mt < MT; ++mt) {
#pragma unroll
        for (int r = 0; r < 16; ++r) {
            const int row = (r & 3) + 8 * (r >> 2) + 4 * (lane >> 5);
            const int px  = x0 + (wm * MT + mt) * 32 + row;
            const int co  = wn * 32 + (lane & 31);
            out[((size_t)(d * 256 + y) * 256 + px) * CO + co] = f2bf(fmaxf(acc[mt][r], 0.f));
        }
    }
}

// conv3d 32->1, bf16 in, wt2 fp32 [kpos][ci]
__global__ __launch_bounds__(256) void omni_reg2(
        const ushort_t* __restrict__ in, const float* __restrict__ wt2,
        float* __restrict__ out) {
    __shared__ float wl[27 * 32];
    int tid = threadIdx.x;
    for (int i = tid; i < 864; i += 256) wl[i] = wt2[i];
    __syncthreads();
    int gid = blockIdx.x * 256 + tid;               // 4*256*256
    int x = gid & 255;
    int y = (gid >> 8) & 255;
    int d = gid >> 16;
    float acc = 0.f;
    for (int kd = 0; kd < 3; kd++) {
        int dd = d + kd - 1; if (dd < 0 || dd > 3) continue;
        for (int ky = 0; ky < 3; ky++) {
            int yy = y + ky - 1; if (yy < 0 || yy > 255) continue;
            for (int kx = 0; kx < 3; kx++) {
                int xx = x + kx - 1; if (xx < 0 || xx > 255) continue;
                const uint4* f4 = (const uint4*)(in + (((size_t)dd * 256 + yy) * 256 + xx) * 32);
                const float* wp = &wl[((kd * 3 + ky) * 3 + kx) * 32];
#pragma unroll
                for (int q = 0; q < 4; q++) {
                    uint4 v = f4[q];
                    float2 p0 = bfp(v.x), p1 = bfp(v.y), p2 = bfp(v.z), p3 = bfp(v.w);
                    acc += p0.x * wp[8*q+0] + p0.y * wp[8*q+1]
                         + p1.x * wp[8*q+2] + p1.y * wp[8*q+3]
                         + p2.x * wp[8*q+4] + p2.y * wp[8*q+5]
                         + p3.x * wp[8*q+6] + p3.y * wp[8*q+7];
                }
            }
        }
    }
    out[gid] = acc;
}

// depth resize 4->8 + softmax + expectation
__global__ __launch_bounds__(256) void omni_disp(
        const float* __restrict__ x3, float* __restrict__ out) {
    int gid = blockIdx.x * 256 + threadIdx.x;       // 65536
    float v0 = x3[gid];
    float v1 = x3[65536 + gid];
    float v2 = x3[2 * 65536 + gid];
    float v3 = x3[3 * 65536 + gid];
    float l[8];
    l[0] = v0;
    l[1] = 0.75f * v0 + 0.25f * v1;
    l[2] = 0.25f * v0 + 0.75f * v1;
    l[3] = 0.75f * v1 + 0.25f * v2;
    l[4] = 0.25f * v1 + 0.75f * v2;
    l[5] = 0.75f * v2 + 0.25f * v3;
    l[6] = 0.25f * v2 + 0.75f * v3;
    l[7] = v3;
    float m = l[0];
#pragma unroll
    for (int i = 1; i < 8; i++) m = fmaxf(m, l[i]);
    float s = 0.f, e = 0.f;
#pragma unroll
    for (int i = 0; i < 8; i++) {
        float p = expf(l[i] - m);
        s += p; e += p * (float)i;
    }
    out[gid] = e / s;
}

extern "C" void kernel_launch(void* const* d_in, const int* in_sizes, int n_in,
                              void* d_out, int out_size, void* d_ws, size_t ws_size,
                              hipStream_t stream) {
    const float* cam0 = (const float*)d_in[0];
    const float* cam1 = (const float*)d_in[1];
    const float* cam2 = (const float*)d_in[2];
    const float* cam3 = (const float*)d_in[3];
    const float* grids = (const float*)d_in[4];
    const float* w_feat = (const float*)d_in[5];
    const float* w_fusion = (const float*)d_in[6];
    const float* w_reg1 = (const float*)d_in[7];
    const float* w_reg2 = (const float*)d_in[8];

    char* base = (char*)d_ws;
    ushort_t* feat  = (ushort_t*)(base);
    ushort_t* costs = (ushort_t*)(base + 52428800);
    ushort_t* x1    = (ushort_t*)(base + 119537664);
    ushort_t* x2    = (ushort_t*)(base + 153092096);
    float*    x3    = (float*)   (base + 169869312);
    ushort_t* wbf   = (ushort_t*)(base + 170917888);
    ushort_t* wb1   = (ushort_t*)(base + 171360256);
    float*    wt2   = (float*)   (base + 171470848);

    omni_pack_w<128, 64><<<864, 256, 0, stream>>>(w_fusion, wbf);
    omni_pack_w<64, 32><<<216, 256, 0, stream>>>(w_reg1, wb1);
    omni_transpose_w<<<4, 256, 0, stream>>>(w_reg2, wt2, 32, 1, 864);

    omni_feat_conv<<<3200, 256, 0, stream>>>(cam0, cam1, cam2, cam3, w_feat, feat);
    omni_warp_resize<<<4096, 256, 0, stream>>>(feat, grids, costs);
    omni_conv3d_mfma<128, 64><<<dim3(2, 256, 4), 256, 0, stream>>>(costs, wbf, x1);
    omni_conv3d_mfma<64, 32><<<dim3(2, 256, 4), 256, 0, stream>>>(x1, wb1, x2);
    omni_reg2<<<1024, 256, 0, stream>>>(x2, wt2, x3);
    omni_disp<<<256, 256, 0, stream>>>(x3, (float*)d_out);
}

// Round 3
// 630.635 us; speedup vs baseline: 16.7888x; 1.7253x over previous
//
#include <hip/hip_runtime.h>

typedef __attribute__((ext_vector_type(8))) __bf16 bfrag;
typedef __attribute__((ext_vector_type(16))) float f32x16;
typedef unsigned short ushort_t;

__device__ __forceinline__ unsigned short f2bf(float f) {
    union { unsigned int u; float f; } c; c.f = f;
    unsigned int u = c.u;
    return (unsigned short)((u + 0x7FFFu + ((u >> 16) & 1u)) >> 16);
}
__device__ __forceinline__ float2 bfp(unsigned int u) {
    union { unsigned int u; float f; } lo, hi;
    lo.u = u << 16; hi.u = u & 0xFFFF0000u;
    return make_float2(lo.f, hi.f);
}
__device__ __forceinline__ unsigned int pk2(float a, float b) {
    return ((unsigned)f2bf(b) << 16) | f2bf(a);
}

// ---------------- workspace layout (bytes) ----------------
// feat  bf16 [4][320][640][32]   at 0          (52,428,800)
// costs bf16 [4][256][256][128]  at 52428800   (67,108,864)
// x1    bf16 [4][256][256][64]   at 119537664  (33,554,432)
// x2    bf16 [4][256][256][32]   at 153092096  (16,777,216)
// x3    f32  [4][256][256]       at 169869312  (1,048,576)
// wbf   bf16 packed fusion       at 170917888  (442,368)
// wb1   bf16 packed reg1         at 171360256  (110,592)
// wt2   f32  [kpos][32]          at 171470848  (3,456)

__global__ void omni_transpose_w(const float* __restrict__ src, float* __restrict__ dst,
                                 int cin, int cout, int n) {
    int i = blockIdx.x * 256 + threadIdx.x;
    if (i >= n) return;
    int co = i % cout;
    int t  = i / cout;
    int ci = t % cin;
    int kpos = t / cin;
    dst[i] = src[(co * cin + ci) * 27 + kpos];
}

// pack conv3d weights (OIDHW fp32) into MFMA B-fragment order, bf16.
// layout: [p = c*3+kd][f = tap*4+ks][wn][lane][8]
template<int CI, int CO>
__global__ void omni_pack_w(const float* __restrict__ w, ushort_t* __restrict__ dst) {
    constexpr int WN = CO / 32;
    const int n = (CI / 64) * 3 * 36 * WN * 512;
    int o = blockIdx.x * 256 + threadIdx.x;
    if (o >= n) return;
    const int j = o & 7;
    const int lane = (o >> 3) & 63;
    int r = o >> 9;
    const int wn = r % WN; r /= WN;
    const int f = r % 36;  const int p = r / 36;
    const int tap = f >> 2, ks = f & 3;
    const int c = p / 3, kd = p % 3;
    const int co = wn * 32 + (lane & 31);
    const int ci = c * 64 + ks * 16 + (lane >> 5) * 8 + j;
    const int ky = tap / 3, kx = tap % 3;
    dst[o] = f2bf(w[(((size_t)(co * CI + ci) * 3 + kd) * 3 + ky) * 3 + kx]);
}

// conv2d stride2 pad1 + relu; input NCHW [3,640,1280]; out bf16 channels-last [cam][320][640][32]
__global__ __launch_bounds__(256) void omni_feat_conv(
        const float* __restrict__ c0, const float* __restrict__ c1,
        const float* __restrict__ c2, const float* __restrict__ c3,
        const float* __restrict__ w, ushort_t* __restrict__ feat) {
    __shared__ float wl[864];
    int tid = threadIdx.x;
    for (int i = tid; i < 864; i += 256) wl[i] = w[i];
    __syncthreads();
    int gid = blockIdx.x * 256 + tid;               // 4*320*640
    int ox = gid % 640;
    int t = gid / 640;
    int oy = t % 320;
    int cam = t / 320;
    const float* src = (cam == 0) ? c0 : (cam == 1) ? c1 : (cam == 2) ? c2 : c3;
    float acc[32];
#pragma unroll
    for (int i = 0; i < 32; i++) acc[i] = 0.f;
    for (int ky = 0; ky < 3; ky++) {
        int iy = oy * 2 - 1 + ky;
        if (iy < 0 || iy >= 640) continue;
        for (int kx = 0; kx < 3; kx++) {
            int ix = ox * 2 - 1 + kx;
            if (ix < 0 || ix >= 1280) continue;
#pragma unroll
            for (int ci = 0; ci < 3; ci++) {
                float v = src[(ci * 640 + iy) * 1280 + ix];
#pragma unroll
                for (int co = 0; co < 32; co++)
                    acc[co] += v * wl[((co * 3 + ci) * 3 + ky) * 3 + kx];
            }
        }
    }
    uint4* d4 = (uint4*)(feat + (size_t)gid * 32);
#pragma unroll
    for (int q = 0; q < 4; q++) {
        uint4 v;
        v.x = pk2(fmaxf(acc[8*q+0],0.f), fmaxf(acc[8*q+1],0.f));
        v.y = pk2(fmaxf(acc[8*q+2],0.f), fmaxf(acc[8*q+3],0.f));
        v.z = pk2(fmaxf(acc[8*q+4],0.f), fmaxf(acc[8*q+5],0.f));
        v.w = pk2(fmaxf(acc[8*q+6],0.f), fmaxf(acc[8*q+7],0.f));
        d4[q] = v;
    }
}

// Tiled fused grid_sample + antialiased resize.
// Block = one (cam,d) x 32x8 output tile. Stage 1: sample the 12x83 source
// window ONCE into LDS (4 gathers/position). Stage 2: 15-tap resize from LDS.
#define NXP 83
#define NYP 12
#define NPOS (NXP * NYP)   // 996
__global__ __launch_bounds__(256) void omni_warp_resize(
        const ushort_t* __restrict__ feat, const float* __restrict__ grids,
        ushort_t* __restrict__ costs) {
    __shared__ ushort_t smp[NPOS * 32];   // [pos][q-swizzled 4x16B] = 63,744 B
    const int tid = threadIdx.x;
    const int bid = blockIdx.x;
    const int tx  = bid & 7;
    const int ty  = (bid >> 3) & 31;
    const int d   = (bid >> 8) & 3;
    const int cam = bid >> 10;
    const int x0 = tx * 32, y0 = ty * 8;
    const int jx_base = (int)ceilf(2.5f * x0 - 1.75f);
    const int jy_base = (int)ceilf(1.25f * y0 - 1.125f);
    const float* gbase = grids + ((size_t)(cam * 4 + d) * 320) * 640 * 2;
    const ushort_t* fbase = feat + (size_t)cam * 320 * 640 * 32;

    // ---- stage 1: grid_sample source window into LDS ----
    for (int i = tid; i < NPOS; i += 256) {
        const int jy = jy_base + i / NXP;
        const int jx = jx_base + i % NXP;
        float acc[32];
#pragma unroll
        for (int c = 0; c < 32; c++) acc[c] = 0.f;
        if ((unsigned)jy < 320u && (unsigned)jx < 640u) {
            const float gx = gbase[((size_t)jy * 640 + jx) * 2];
            const float gy = gbase[((size_t)jy * 640 + jx) * 2 + 1];
            const float fx = (gx + 1.f) * 320.f - 0.5f;
            const float fy = (gy + 1.f) * 160.f - 0.5f;
            const float x0f = floorf(fx), y0f = floorf(fy);
            const float ax = fx - x0f, ay = fy - y0f;
            const int sx0 = (int)x0f, sy0 = (int)y0f;
            const float tw[4] = {(1.f-ax)*(1.f-ay), ax*(1.f-ay), (1.f-ax)*ay, ax*ay};
            const int xs4[4] = {sx0, sx0+1, sx0, sx0+1};
            const int ys4[4] = {sy0, sy0, sy0+1, sy0+1};
#pragma unroll
            for (int tc = 0; tc < 4; tc++) {
                const int xi = xs4[tc], yi = ys4[tc];
                if (xi < 0 || xi >= 640 || yi < 0 || yi >= 320) continue;
                const float wt = tw[tc];
                const uint4* f4 = (const uint4*)(fbase + ((size_t)yi * 640 + xi) * 32);
#pragma unroll
                for (int q = 0; q < 4; q++) {
                    uint4 v = f4[q];
                    float2 p0 = bfp(v.x), p1 = bfp(v.y), p2 = bfp(v.z), p3 = bfp(v.w);
                    acc[8*q+0] += wt * p0.x; acc[8*q+1] += wt * p0.y;
                    acc[8*q+2] += wt * p1.x; acc[8*q+3] += wt * p1.y;
                    acc[8*q+4] += wt * p2.x; acc[8*q+5] += wt * p2.y;
                    acc[8*q+6] += wt * p3.x; acc[8*q+7] += wt * p3.y;
                }
            }
        }
#pragma unroll
        for (int q = 0; q < 4; q++) {
            uint4 v;
            v.x = pk2(acc[8*q+0], acc[8*q+1]);
            v.y = pk2(acc[8*q+2], acc[8*q+3]);
            v.z = pk2(acc[8*q+4], acc[8*q+5]);
            v.w = pk2(acc[8*q+6], acc[8*q+7]);
            *(uint4*)&smp[i * 32 + ((q ^ (i & 3)) * 8)] = v;
        }
    }
    __syncthreads();

    // ---- stage 2: antialiased resize from LDS ----
    const int x = x0 + (tid & 31);
    const int y = y0 + (tid >> 5);

    const float sy = 1.25f * y + 0.125f;
    const int jy0 = (int)ceilf(sy - 1.25f);
    float wy[3]; float sumy = 0.f;
#pragma unroll
    for (int t = 0; t < 3; t++) {
        int j = jy0 + t;
        float w = fmaxf(1.f - fabsf(sy - (float)j) * 0.8f, 0.f);
        if (j < 0 || j > 319) w = 0.f;
        wy[t] = w; sumy += w;
    }
    const float isy = 1.f / sumy;
    const float sx = 2.5f * x + 0.75f;
    const int jx0 = (int)ceilf(sx - 2.5f);
    float wx[5]; float sumx = 0.f;
#pragma unroll
    for (int t = 0; t < 5; t++) {
        int j = jx0 + t;
        float w = fmaxf(1.f - fabsf(sx - (float)j) * 0.4f, 0.f);
        if (j < 0 || j > 639) w = 0.f;
        wx[t] = w; sumx += w;
    }
    const float isx = 1.f / sumx;

    float acc[32];
#pragma unroll
    for (int c = 0; c < 32; c++) acc[c] = 0.f;
#pragma unroll
    for (int a = 0; a < 3; a++) {
        const float wya = wy[a] * isy;
        if (wya <= 0.f) continue;
        const int prow = (jy0 + a) - jy_base;
#pragma unroll
        for (int b = 0; b < 5; b++) {
            const float wr = wya * wx[b] * isx;
            if (wr <= 0.f) continue;
            const int pos = prow * NXP + (jx0 + b) - jx_base;
#pragma unroll
            for (int q = 0; q < 4; q++) {
                uint4 v = *(const uint4*)&smp[pos * 32 + ((q ^ (pos & 3)) * 8)];
                float2 p0 = bfp(v.x), p1 = bfp(v.y), p2 = bfp(v.z), p3 = bfp(v.w);
                acc[8*q+0] += wr * p0.x; acc[8*q+1] += wr * p0.y;
                acc[8*q+2] += wr * p1.x; acc[8*q+3] += wr * p1.y;
                acc[8*q+4] += wr * p2.x; acc[8*q+5] += wr * p2.y;
                acc[8*q+6] += wr * p3.x; acc[8*q+7] += wr * p3.y;
            }
        }
    }
    uint4* d4 = (uint4*)(costs + (((size_t)(d * 256 + y) * 256 + x) * 128) + cam * 32);
#pragma unroll
    for (int q = 0; q < 4; q++) {
        uint4 v;
        v.x = pk2(acc[8*q+0], acc[8*q+1]);
        v.y = pk2(acc[8*q+2], acc[8*q+3]);
        v.z = pk2(acc[8*q+4], acc[8*q+5]);
        v.w = pk2(acc[8*q+6], acc[8*q+7]);
        d4[q] = v;
    }
}

// MFMA implicit-GEMM conv3d (3x3x3, pad1) channels-last bf16, relu.
template<int CI, int CO>
__global__ __launch_bounds__(256, 2) void omni_conv3d_mfma(
        const ushort_t* __restrict__ in,
        const ushort_t* __restrict__ wb,
        ushort_t* __restrict__ out) {
    constexpr int WN = CO / 32;
    constexpr int MT = (WN == 2) ? 2 : 1;
    __shared__ ushort_t lds[3 * 130 * 64];
    const int tid = threadIdx.x;
    const int lane = tid & 63;
    const int wid = tid >> 6;
    const int wn = wid & (WN - 1);
    const int wm = wid / WN;
    const int x0 = blockIdx.x * 128;
    const int y  = blockIdx.y;
    const int d  = blockIdx.z;

    f32x16 acc[MT];
#pragma unroll
    for (int mt = 0; mt < MT; ++mt)
#pragma unroll
        for (int r = 0; r < 16; ++r) acc[mt][r] = 0.f;

    bfrag breg[36];

    for (int c = 0; c < CI / 64; ++c) {
        for (int kd = 0; kd < 3; ++kd) {
            const int dd = d + kd - 1;
            if (dd < 0 || dd > 3) continue;
            __syncthreads();
            for (int i = tid; i < 3120; i += 256) {
                const int g  = i & 7;
                const int xl = (i >> 3) % 130;
                const int yy = (i >> 3) / 130;
                const int gy = y - 1 + yy;
                const int gx = x0 - 1 + xl;
                uint4 v = make_uint4(0u, 0u, 0u, 0u);
                if ((unsigned)gy < 256u && (unsigned)gx < 256u)
                    v = *(const uint4*)(in + (((size_t)dd * 256 + gy) * 256 + gx) * CI + c * 64 + g * 8);
                *(uint4*)&lds[((yy * 130 + xl) * 8 + (g ^ (xl & 7))) * 8] = v;
            }
            const int p = c * 3 + kd;
#pragma unroll
            for (int f = 0; f < 36; ++f)
                breg[f] = *(const bfrag*)(wb + (((size_t)p * 36 + f) * WN + wn) * 512 + lane * 8);
            __syncthreads();
#pragma unroll
            for (int ky = 0; ky < 3; ++ky) {
                const int gyy = y - 1 + ky;
                if ((unsigned)gyy >= 256u) continue;
#pragma unroll
                for (int kx = 0; kx < 3; ++kx) {
#pragma unroll
                    for (int ks = 0; ks < 4; ++ks) {
#pragma unroll
                        for (int mt = 0; mt < MT; ++mt) {
                            const int m  = (wm * MT + mt) * 32 + (lane & 31);
                            const int xl = m + kx;
                            const int g  = ks * 2 + (lane >> 5);
                            const bfrag a = *(const bfrag*)&lds[((ky * 130 + xl) * 8 + (g ^ (xl & 7))) * 8];
                            acc[mt] = __builtin_amdgcn_mfma_f32_32x32x16_bf16(
                                a, breg[(ky * 3 + kx) * 4 + ks], acc[mt], 0, 0, 0);
                        }
                    }
                }
            }
        }
    }
#pragma unroll
    for (int mt = 0; mt < MT; ++mt) {
#pragma unroll
        for (int r = 0; r < 16; ++r) {
            const int row = (r & 3) + 8 * (r >> 2) + 4 * (lane >> 5);
            const int px  = x0 + (wm * MT + mt) * 32 + row;
            const int co  = wn * 32 + (lane & 31);
            out[((size_t)(d * 256 + y) * 256 + px) * CO + co] = f2bf(fmaxf(acc[mt][r], 0.f));
        }
    }
}

// conv3d 32->1, bf16 in, wt2 fp32 [kpos][ci]
__global__ __launch_bounds__(256) void omni_reg2(
        const ushort_t* __restrict__ in, const float* __restrict__ wt2,
        float* __restrict__ out) {
    __shared__ float wl[27 * 32];
    int tid = threadIdx.x;
    for (int i = tid; i < 864; i += 256) wl[i] = wt2[i];
    __syncthreads();
    int gid = blockIdx.x * 256 + tid;               // 4*256*256
    int x = gid & 255;
    int y = (gid >> 8) & 255;
    int d = gid >> 16;
    float acc = 0.f;
    for (int kd = 0; kd < 3; kd++) {
        int dd = d + kd - 1; if (dd < 0 || dd > 3) continue;
        for (int ky = 0; ky < 3; ky++) {
            int yy = y + ky - 1; if (yy < 0 || yy > 255) continue;
            for (int kx = 0; kx < 3; kx++) {
                int xx = x + kx - 1; if (xx < 0 || xx > 255) continue;
                const uint4* f4 = (const uint4*)(in + (((size_t)dd * 256 + yy) * 256 + xx) * 32);
                const float* wp = &wl[((kd * 3 + ky) * 3 + kx) * 32];
#pragma unroll
                for (int q = 0; q < 4; q++) {
                    uint4 v = f4[q];
                    float2 p0 = bfp(v.x), p1 = bfp(v.y), p2 = bfp(v.z), p3 = bfp(v.w);
                    acc += p0.x * wp[8*q+0] + p0.y * wp[8*q+1]
                         + p1.x * wp[8*q+2] + p1.y * wp[8*q+3]
                         + p2.x * wp[8*q+4] + p2.y * wp[8*q+5]
                         + p3.x * wp[8*q+6] + p3.y * wp[8*q+7];
                }
            }
        }
    }
    out[gid] = acc;
}

// depth resize 4->8 + softmax + expectation
__global__ __launch_bounds__(256) void omni_disp(
        const float* __restrict__ x3, float* __restrict__ out) {
    int gid = blockIdx.x * 256 + threadIdx.x;       // 65536
    float v0 = x3[gid];
    float v1 = x3[65536 + gid];
    float v2 = x3[2 * 65536 + gid];
    float v3 = x3[3 * 65536 + gid];
    float l[8];
    l[0] = v0;
    l[1] = 0.75f * v0 + 0.25f * v1;
    l[2] = 0.25f * v0 + 0.75f * v1;
    l[3] = 0.75f * v1 + 0.25f * v2;
    l[4] = 0.25f * v1 + 0.75f * v2;
    l[5] = 0.75f * v2 + 0.25f * v3;
    l[6] = 0.25f * v2 + 0.75f * v3;
    l[7] = v3;
    float m = l[0];
#pragma unroll
    for (int i = 1; i < 8; i++) m = fmaxf(m, l[i]);
    float s = 0.f, e = 0.f;
#pragma unroll
    for (int i = 0; i < 8; i++) {
        float p = expf(l[i] - m);
        s += p; e += p * (float)i;
    }
    out[gid] = e / s;
}

extern "C" void kernel_launch(void* const* d_in, const int* in_sizes, int n_in,
                              void* d_out, int out_size, void* d_ws, size_t ws_size,
                              hipStream_t stream) {
    const float* cam0 = (const float*)d_in[0];
    const float* cam1 = (const float*)d_in[1];
    const float* cam2 = (const float*)d_in[2];
    const float* cam3 = (const float*)d_in[3];
    const float* grids = (const float*)d_in[4];
    const float* w_feat = (const float*)d_in[5];
    const float* w_fusion = (const float*)d_in[6];
    const float* w_reg1 = (const float*)d_in[7];
    const float* w_reg2 = (const float*)d_in[8];

    char* base = (char*)d_ws;
    ushort_t* feat  = (ushort_t*)(base);
    ushort_t* costs = (ushort_t*)(base + 52428800);
    ushort_t* x1    = (ushort_t*)(base + 119537664);
    ushort_t* x2    = (ushort_t*)(base + 153092096);
    float*    x3    = (float*)   (base + 169869312);
    ushort_t* wbf   = (ushort_t*)(base + 170917888);
    ushort_t* wb1   = (ushort_t*)(base + 171360256);
    float*    wt2   = (float*)   (base + 171470848);

    omni_pack_w<128, 64><<<864, 256, 0, stream>>>(w_fusion, wbf);
    omni_pack_w<64, 32><<<216, 256, 0, stream>>>(w_reg1, wb1);
    omni_transpose_w<<<4, 256, 0, stream>>>(w_reg2, wt2, 32, 1, 864);

    omni_feat_conv<<<3200, 256, 0, stream>>>(cam0, cam1, cam2, cam3, w_feat, feat);
    omni_warp_resize<<<4096, 256, 0, stream>>>(feat, grids, costs);
    omni_conv3d_mfma<128, 64><<<dim3(2, 256, 4), 256, 0, stream>>>(costs, wbf, x1);
    omni_conv3d_mfma<64, 32><<<dim3(2, 256, 4), 256, 0, stream>>>(x1, wb1, x2);
    omni_reg2<<<1024, 256, 0, stream>>>(x2, wt2, x3);
    omni_disp<<<256, 256, 0, stream>>>(x3, (float*)d_out);
}

// Round 4
// 616.209 us; speedup vs baseline: 17.1819x; 1.0234x over previous
//
#include <hip/hip_runtime.h>

typedef __attribute__((ext_vector_type(8))) __bf16 bfrag;
typedef __attribute__((ext_vector_type(16))) float f32x16;
typedef unsigned short ushort_t;

__device__ __forceinline__ unsigned short f2bf(float f) {
    union { unsigned int u; float f; } c; c.f = f;
    unsigned int u = c.u;
    return (unsigned short)((u + 0x7FFFu + ((u >> 16) & 1u)) >> 16);
}
__device__ __forceinline__ float2 bfp(unsigned int u) {
    union { unsigned int u; float f; } lo, hi;
    lo.u = u << 16; hi.u = u & 0xFFFF0000u;
    return make_float2(lo.f, hi.f);
}
__device__ __forceinline__ unsigned int pk2(float a, float b) {
    return ((unsigned)f2bf(b) << 16) | f2bf(a);
}

// ---------------- workspace layout (bytes) ----------------
// feat  bf16 [4][320][640][32]   at 0          (52,428,800)
// costs bf16 [4][256][256][128]  at 52428800   (67,108,864)
// x1    bf16 [4][256][256][64]   at 119537664  (33,554,432)
// x2    bf16 [4][256][256][32]   at 153092096  (16,777,216)
// x3    f32  [4][256][256]       at 169869312  (1,048,576)
// wbf   bf16 packed fusion       at 170917888  (442,368)
// wb1   bf16 packed reg1         at 171360256  (110,592)
// wt2   f32  [kpos][32]          at 171470848  (3,456)

__global__ void omni_transpose_w(const float* __restrict__ src, float* __restrict__ dst,
                                 int cin, int cout, int n) {
    int i = blockIdx.x * 256 + threadIdx.x;
    if (i >= n) return;
    int co = i % cout;
    int t  = i / cout;
    int ci = t % cin;
    int kpos = t / cin;
    dst[i] = src[(co * cin + ci) * 27 + kpos];
}

// pack conv3d weights (OIDHW fp32) into MFMA B-fragment order, bf16.
// layout: [p = c*3+kd][f = tap*4+ks][wn][lane][8]
template<int CI, int CO>
__global__ void omni_pack_w(const float* __restrict__ w, ushort_t* __restrict__ dst) {
    constexpr int WN = CO / 32;
    const int n = (CI / 64) * 3 * 36 * WN * 512;
    int o = blockIdx.x * 256 + threadIdx.x;
    if (o >= n) return;
    const int j = o & 7;
    const int lane = (o >> 3) & 63;
    int r = o >> 9;
    const int wn = r % WN; r /= WN;
    const int f = r % 36;  const int p = r / 36;
    const int tap = f >> 2, ks = f & 3;
    const int c = p / 3, kd = p % 3;
    const int co = wn * 32 + (lane & 31);
    const int ci = c * 64 + ks * 16 + (lane >> 5) * 8 + j;
    const int ky = tap / 3, kx = tap % 3;
    dst[o] = f2bf(w[(((size_t)(co * CI + ci) * 3 + kd) * 3 + ky) * 3 + kx]);
}

// conv2d stride2 pad1 + relu; input NCHW [3,640,1280]; out bf16 channels-last [cam][320][640][32]
__global__ __launch_bounds__(256) void omni_feat_conv(
        const float* __restrict__ c0, const float* __restrict__ c1,
        const float* __restrict__ c2, const float* __restrict__ c3,
        const float* __restrict__ w, ushort_t* __restrict__ feat) {
    __shared__ float wl[864];
    int tid = threadIdx.x;
    for (int i = tid; i < 864; i += 256) wl[i] = w[i];
    __syncthreads();
    int gid = blockIdx.x * 256 + tid;               // 4*320*640
    int ox = gid % 640;
    int t = gid / 640;
    int oy = t % 320;
    int cam = t / 320;
    const float* src = (cam == 0) ? c0 : (cam == 1) ? c1 : (cam == 2) ? c2 : c3;
    float acc[32];
#pragma unroll
    for (int i = 0; i < 32; i++) acc[i] = 0.f;
    for (int ky = 0; ky < 3; ky++) {
        int iy = oy * 2 - 1 + ky;
        if (iy < 0 || iy >= 640) continue;
        for (int kx = 0; kx < 3; kx++) {
            int ix = ox * 2 - 1 + kx;
            if (ix < 0 || ix >= 1280) continue;
#pragma unroll
            for (int ci = 0; ci < 3; ci++) {
                float v = src[(ci * 640 + iy) * 1280 + ix];
#pragma unroll
                for (int co = 0; co < 32; co++)
                    acc[co] += v * wl[((co * 3 + ci) * 3 + ky) * 3 + kx];
            }
        }
    }
    uint4* d4 = (uint4*)(feat + (size_t)gid * 32);
#pragma unroll
    for (int q = 0; q < 4; q++) {
        uint4 v;
        v.x = pk2(fmaxf(acc[8*q+0],0.f), fmaxf(acc[8*q+1],0.f));
        v.y = pk2(fmaxf(acc[8*q+2],0.f), fmaxf(acc[8*q+3],0.f));
        v.z = pk2(fmaxf(acc[8*q+4],0.f), fmaxf(acc[8*q+5],0.f));
        v.w = pk2(fmaxf(acc[8*q+6],0.f), fmaxf(acc[8*q+7],0.f));
        d4[q] = v;
    }
}

// Tiled fused grid_sample + antialiased resize.
// Block = one (cam,d) x 16x8 output tile. Stage 1: sample the 42x12 source
// window ONCE into LDS q-major [q][pos] (conflict-free). Stage 2: 15-tap
// resize from LDS, channels split across two 128-thread halves.
#define NXP 42
#define NYP 12
#define NPOS (NXP * NYP)   // 504
__global__ __launch_bounds__(256) void omni_warp_resize(
        const ushort_t* __restrict__ feat, const float* __restrict__ grids,
        ushort_t* __restrict__ costs) {
    __shared__ uint4 smp4[4 * NPOS];   // 32,256 B -> 4 blocks/CU
    const int tid = threadIdx.x;
    const int bid = blockIdx.x;
    const int tx  = bid & 15;
    const int ty  = (bid >> 4) & 31;
    const int d   = (bid >> 9) & 3;
    const int cam = bid >> 11;
    const int x0 = tx * 16, y0 = ty * 8;
    const int jx_base = 40 * tx - 1;   // = ceil(2.5*x0 - 1.75)
    const int jy_base = 10 * ty - 1;   // = ceil(1.25*y0 - 1.125)
    const float* gbase = grids + ((size_t)(cam * 4 + d) * 320) * 640 * 2;
    const ushort_t* fbase = feat + (size_t)cam * 320 * 640 * 32;

    // ---- stage 1: grid_sample source window into LDS ----
    for (int i = tid; i < NPOS; i += 256) {
        const int jy = jy_base + i / NXP;
        const int jx = jx_base + i % NXP;
        float acc[32];
#pragma unroll
        for (int c = 0; c < 32; c++) acc[c] = 0.f;
        if ((unsigned)jy < 320u && (unsigned)jx < 640u) {
            const float gx = gbase[((size_t)jy * 640 + jx) * 2];
            const float gy = gbase[((size_t)jy * 640 + jx) * 2 + 1];
            const float fx = (gx + 1.f) * 320.f - 0.5f;
            const float fy = (gy + 1.f) * 160.f - 0.5f;
            const float x0f = floorf(fx), y0f = floorf(fy);
            const float ax = fx - x0f, ay = fy - y0f;
            const int sx0 = (int)x0f, sy0 = (int)y0f;
            const float tw[4] = {(1.f-ax)*(1.f-ay), ax*(1.f-ay), (1.f-ax)*ay, ax*ay};
            const int xs4[4] = {sx0, sx0+1, sx0, sx0+1};
            const int ys4[4] = {sy0, sy0, sy0+1, sy0+1};
#pragma unroll
            for (int tc = 0; tc < 4; tc++) {
                const int xi = xs4[tc], yi = ys4[tc];
                if (xi < 0 || xi >= 640 || yi < 0 || yi >= 320) continue;
                const float wt = tw[tc];
                const uint4* f4 = (const uint4*)(fbase + ((size_t)yi * 640 + xi) * 32);
#pragma unroll
                for (int q = 0; q < 4; q++) {
                    uint4 v = f4[q];
                    float2 p0 = bfp(v.x), p1 = bfp(v.y), p2 = bfp(v.z), p3 = bfp(v.w);
                    acc[8*q+0] += wt * p0.x; acc[8*q+1] += wt * p0.y;
                    acc[8*q+2] += wt * p1.x; acc[8*q+3] += wt * p1.y;
                    acc[8*q+4] += wt * p2.x; acc[8*q+5] += wt * p2.y;
                    acc[8*q+6] += wt * p3.x; acc[8*q+7] += wt * p3.y;
                }
            }
        }
#pragma unroll
        for (int q = 0; q < 4; q++) {
            uint4 v;
            v.x = pk2(acc[8*q+0], acc[8*q+1]);
            v.y = pk2(acc[8*q+2], acc[8*q+3]);
            v.z = pk2(acc[8*q+4], acc[8*q+5]);
            v.w = pk2(acc[8*q+6], acc[8*q+7]);
            smp4[q * NPOS + i] = v;
        }
    }
    __syncthreads();

    // ---- stage 2: antialiased resize from LDS ----
    const int half = tid >> 7;          // channel half: q in {2*half, 2*half+1}
    const int p = tid & 127;
    const int x = x0 + (p & 15);
    const int y = y0 + (p >> 4);

    const float sy = 1.25f * y + 0.125f;
    const int jy0 = (int)ceilf(sy - 1.25f);
    float wy[3]; float sumy = 0.f;
#pragma unroll
    for (int t = 0; t < 3; t++) {
        int j = jy0 + t;
        float w = fmaxf(1.f - fabsf(sy - (float)j) * 0.8f, 0.f);
        if (j < 0 || j > 319) w = 0.f;
        wy[t] = w; sumy += w;
    }
    const float isy = 1.f / sumy;
    const float sx = 2.5f * x + 0.75f;
    const int jx0 = (int)ceilf(sx - 2.5f);
    float wx[5]; float sumx = 0.f;
#pragma unroll
    for (int t = 0; t < 5; t++) {
        int j = jx0 + t;
        float w = fmaxf(1.f - fabsf(sx - (float)j) * 0.4f, 0.f);
        if (j < 0 || j > 639) w = 0.f;
        wx[t] = w; sumx += w;
    }
    const float isx = 1.f / sumx;

    float acc[16];
#pragma unroll
    for (int c = 0; c < 16; c++) acc[c] = 0.f;
#pragma unroll
    for (int a = 0; a < 3; a++) {
        const float wya = wy[a] * isy;
        if (wya <= 0.f) continue;
        const int prow = (jy0 + a) - jy_base;
#pragma unroll
        for (int b = 0; b < 5; b++) {
            const float wr = wya * wx[b] * isx;
            if (wr <= 0.f) continue;
            const int pos = prow * NXP + (jx0 + b) - jx_base;
#pragma unroll
            for (int qq = 0; qq < 2; qq++) {
                uint4 v = smp4[(half * 2 + qq) * NPOS + pos];
                float2 p0 = bfp(v.x), p1 = bfp(v.y), p2 = bfp(v.z), p3 = bfp(v.w);
                acc[8*qq+0] += wr * p0.x; acc[8*qq+1] += wr * p0.y;
                acc[8*qq+2] += wr * p1.x; acc[8*qq+3] += wr * p1.y;
                acc[8*qq+4] += wr * p2.x; acc[8*qq+5] += wr * p2.y;
                acc[8*qq+6] += wr * p3.x; acc[8*qq+7] += wr * p3.y;
            }
        }
    }
    uint4* d4 = (uint4*)(costs + (((size_t)(d * 256 + y) * 256 + x) * 128) + cam * 32 + half * 16);
#pragma unroll
    for (int qq = 0; qq < 2; qq++) {
        uint4 v;
        v.x = pk2(acc[8*qq+0], acc[8*qq+1]);
        v.y = pk2(acc[8*qq+2], acc[8*qq+3]);
        v.z = pk2(acc[8*qq+4], acc[8*qq+5]);
        v.w = pk2(acc[8*qq+6], acc[8*qq+7]);
        d4[qq] = v;
    }
}

// MFMA implicit-GEMM conv3d (3x3x3, pad1) channels-last bf16, relu.
template<int CI, int CO>
__global__ __launch_bounds__(256, 2) void omni_conv3d_mfma(
        const ushort_t* __restrict__ in,
        const ushort_t* __restrict__ wb,
        ushort_t* __restrict__ out) {
    constexpr int WN = CO / 32;
    constexpr int MT = (WN == 2) ? 2 : 1;
    __shared__ ushort_t lds[3 * 130 * 64];
    const int tid = threadIdx.x;
    const int lane = tid & 63;
    const int wid = tid >> 6;
    const int wn = wid & (WN - 1);
    const int wm = wid / WN;
    const int x0 = blockIdx.x * 128;
    const int y  = blockIdx.y;
    const int d  = blockIdx.z;

    f32x16 acc[MT];
#pragma unroll
    for (int mt = 0; mt < MT; ++mt)
#pragma unroll
        for (int r = 0; r < 16; ++r) acc[mt][r] = 0.f;

    bfrag breg[36];

    for (int c = 0; c < CI / 64; ++c) {
        for (int kd = 0; kd < 3; ++kd) {
            const int dd = d + kd - 1;
            if (dd < 0 || dd > 3) continue;
            __syncthreads();
            for (int i = tid; i < 3120; i += 256) {
                const int g  = i & 7;
                const int xl = (i >> 3) % 130;
                const int yy = (i >> 3) / 130;
                const int gy = y - 1 + yy;
                const int gx = x0 - 1 + xl;
                uint4 v = make_uint4(0u, 0u, 0u, 0u);
                if ((unsigned)gy < 256u && (unsigned)gx < 256u)
                    v = *(const uint4*)(in + (((size_t)dd * 256 + gy) * 256 + gx) * CI + c * 64 + g * 8);
                *(uint4*)&lds[((yy * 130 + xl) * 8 + (g ^ (xl & 7))) * 8] = v;
            }
            const int p = c * 3 + kd;
#pragma unroll
            for (int f = 0; f < 36; ++f)
                breg[f] = *(const bfrag*)(wb + (((size_t)p * 36 + f) * WN + wn) * 512 + lane * 8);
            __syncthreads();
#pragma unroll
            for (int ky = 0; ky < 3; ++ky) {
                const int gyy = y - 1 + ky;
                if ((unsigned)gyy >= 256u) continue;
#pragma unroll
                for (int kx = 0; kx < 3; ++kx) {
#pragma unroll
                    for (int ks = 0; ks < 4; ++ks) {
#pragma unroll
                        for (int mt = 0; mt < MT; ++mt) {
                            const int m  = (wm * MT + mt) * 32 + (lane & 31);
                            const int xl = m + kx;
                            const int g  = ks * 2 + (lane >> 5);
                            const bfrag a = *(const bfrag*)&lds[((ky * 130 + xl) * 8 + (g ^ (xl & 7))) * 8];
                            acc[mt] = __builtin_amdgcn_mfma_f32_32x32x16_bf16(
                                a, breg[(ky * 3 + kx) * 4 + ks], acc[mt], 0, 0, 0);
                        }
                    }
                }
            }
        }
    }
#pragma unroll
    for (int mt = 0; mt < MT; ++mt) {
#pragma unroll
        for (int r = 0; r < 16; ++r) {
            const int row = (r & 3) + 8 * (r >> 2) + 4 * (lane >> 5);
            const int px  = x0 + (wm * MT + mt) * 32 + row;
            const int co  = wn * 32 + (lane & 31);
            out[((size_t)(d * 256 + y) * 256 + px) * CO + co] = f2bf(fmaxf(acc[mt][r], 0.f));
        }
    }
}

// conv3d 32->1, bf16 in, wt2 fp32 [kpos][ci]
__global__ __launch_bounds__(256) void omni_reg2(
        const ushort_t* __restrict__ in, const float* __restrict__ wt2,
        float* __restrict__ out) {
    __shared__ float wl[27 * 32];
    int tid = threadIdx.x;
    for (int i = tid; i < 864; i += 256) wl[i] = wt2[i];
    __syncthreads();
    int gid = blockIdx.x * 256 + tid;               // 4*256*256
    int x = gid & 255;
    int y = (gid >> 8) & 255;
    int d = gid >> 16;
    float acc = 0.f;
    for (int kd = 0; kd < 3; kd++) {
        int dd = d + kd - 1; if (dd < 0 || dd > 3) continue;
        for (int ky = 0; ky < 3; ky++) {
            int yy = y + ky - 1; if (yy < 0 || yy > 255) continue;
            for (int kx = 0; kx < 3; kx++) {
                int xx = x + kx - 1; if (xx < 0 || xx > 255) continue;
                const uint4* f4 = (const uint4*)(in + (((size_t)dd * 256 + yy) * 256 + xx) * 32);
                const float* wp = &wl[((kd * 3 + ky) * 3 + kx) * 32];
#pragma unroll
                for (int q = 0; q < 4; q++) {
                    uint4 v = f4[q];
                    float2 p0 = bfp(v.x), p1 = bfp(v.y), p2 = bfp(v.z), p3 = bfp(v.w);
                    acc += p0.x * wp[8*q+0] + p0.y * wp[8*q+1]
                         + p1.x * wp[8*q+2] + p1.y * wp[8*q+3]
                         + p2.x * wp[8*q+4] + p2.y * wp[8*q+5]
                         + p3.x * wp[8*q+6] + p3.y * wp[8*q+7];
                }
            }
        }
    }
    out[gid] = acc;
}

// depth resize 4->8 + softmax + expectation
__global__ __launch_bounds__(256) void omni_disp(
        const float* __restrict__ x3, float* __restrict__ out) {
    int gid = blockIdx.x * 256 + threadIdx.x;       // 65536
    float v0 = x3[gid];
    float v1 = x3[65536 + gid];
    float v2 = x3[2 * 65536 + gid];
    float v3 = x3[3 * 65536 + gid];
    float l[8];
    l[0] = v0;
    l[1] = 0.75f * v0 + 0.25f * v1;
    l[2] = 0.25f * v0 + 0.75f * v1;
    l[3] = 0.75f * v1 + 0.25f * v2;
    l[4] = 0.25f * v1 + 0.75f * v2;
    l[5] = 0.75f * v2 + 0.25f * v3;
    l[6] = 0.25f * v2 + 0.75f * v3;
    l[7] = v3;
    float m = l[0];
#pragma unroll
    for (int i = 1; i < 8; i++) m = fmaxf(m, l[i]);
    float s = 0.f, e = 0.f;
#pragma unroll
    for (int i = 0; i < 8; i++) {
        float p = expf(l[i] - m);
        s += p; e += p * (float)i;
    }
    out[gid] = e / s;
}

extern "C" void kernel_launch(void* const* d_in, const int* in_sizes, int n_in,
                              void* d_out, int out_size, void* d_ws, size_t ws_size,
                              hipStream_t stream) {
    const float* cam0 = (const float*)d_in[0];
    const float* cam1 = (const float*)d_in[1];
    const float* cam2 = (const float*)d_in[2];
    const float* cam3 = (const float*)d_in[3];
    const float* grids = (const float*)d_in[4];
    const float* w_feat = (const float*)d_in[5];
    const float* w_fusion = (const float*)d_in[6];
    const float* w_reg1 = (const float*)d_in[7];
    const float* w_reg2 = (const float*)d_in[8];

    char* base = (char*)d_ws;
    ushort_t* feat  = (ushort_t*)(base);
    ushort_t* costs = (ushort_t*)(base + 52428800);
    ushort_t* x1    = (ushort_t*)(base + 119537664);
    ushort_t* x2    = (ushort_t*)(base + 153092096);
    float*    x3    = (float*)   (base + 169869312);
    ushort_t* wbf   = (ushort_t*)(base + 170917888);
    ushort_t* wb1   = (ushort_t*)(base + 171360256);
    float*    wt2   = (float*)   (base + 171470848);

    omni_pack_w<128, 64><<<864, 256, 0, stream>>>(w_fusion, wbf);
    omni_pack_w<64, 32><<<216, 256, 0, stream>>>(w_reg1, wb1);
    omni_transpose_w<<<4, 256, 0, stream>>>(w_reg2, wt2, 32, 1, 864);

    omni_feat_conv<<<3200, 256, 0, stream>>>(cam0, cam1, cam2, cam3, w_feat, feat);
    omni_warp_resize<<<8192, 256, 0, stream>>>(feat, grids, costs);
    omni_conv3d_mfma<128, 64><<<dim3(2, 256, 4), 256, 0, stream>>>(costs, wbf, x1);
    omni_conv3d_mfma<64, 32><<<dim3(2, 256, 4), 256, 0, stream>>>(x1, wb1, x2);
    omni_reg2<<<1024, 256, 0, stream>>>(x2, wt2, x3);
    omni_disp<<<256, 256, 0, stream>>>(x3, (float*)d_out);
}